// Round 10
// baseline (275.864 us; speedup 1.0000x reference)
//
#include <hip/hip_runtime.h>
#include <hip/hip_bf16.h>

// Problem constants
#define NB    8
#define SQN   2048
#define SKN   4096
#define DDIM  512
#define DVDIM 256
#define NROWS (NB*SQN)      // 16384
#define NS    2             // SK splits
#define NJ    ((SKN/64)/NS) // 32 j-iterations per split (64 keys each)

typedef __attribute__((ext_vector_type(8)))  short bf16x8;   // 8 bf16 = 4 VGPRs (MFMA A/B frag)
typedef __attribute__((ext_vector_type(4)))  short bf16x4;
typedef __attribute__((ext_vector_type(4)))  float f32x4;    // 16x16 MFMA C/D frag
typedef __attribute__((ext_vector_type(16))) float f32x16;   // 32x32 MFMA C/D frag

// fp32 -> bf16 round-to-nearest-even, bit pattern as short
__device__ __forceinline__ short f2bf(float f) {
    unsigned u = __float_as_uint(f);
    return (short)((u + 0x7FFFu + ((u >> 16) & 1u)) >> 16);
}

// LDS-only barrier: vm loads (K/V register prefetches) stay in flight.
// sched_barrier fences per rule #18 (no hoisting across the asm wait).
#define BAR_LGKM() do {                                                       \
    asm volatile("s_waitcnt lgkmcnt(0)" ::: "memory");                        \
    __builtin_amdgcn_sched_barrier(0);                                        \
    __builtin_amdgcn_s_barrier();                                             \
    __builtin_amdgcn_sched_barrier(0);                                        \
} while (0)

// ---------------------------------------------------------------------------
// Fused projection GEMMs, one launch. grid = (64, 8, 2).  (unchanged from R8)
// Epilogues write K/V PRE-PACKED in fragment-lane order (16B units;
// lane = hi*32 + l31):
//  K: tile ((J*4+c)*8+tp)*2+kh holds K[J*64+kh*32+l31][c*128+tp*16+hi*8+..7]
//  V: tile (J*8+wv*4+n2)*4+g   holds V^T[wv*128+n2*32+l31][J*64+g*16+hi*8+..7]
// ---------------------------------------------------------------------------
__global__ __launch_bounds__(256, 2) void proj_gemms(
    const float* __restrict__ Y, const float* __restrict__ Z,
    const float* __restrict__ Wk, const float* __restrict__ Wv,
    unsigned short* __restrict__ keyb, unsigned short* __restrict__ vtb)
{
    __shared__ short sA[64*128];   // 16 KB
    __shared__ short sB[64*128];   // 16 KB
    const float *A, *Bm;
    unsigned short* C;
    int m0, n0;
    const bool kpath = (blockIdx.z == 0);
    if (kpath) {
        A = Y; Bm = Wk; C = keyb;
        m0 = blockIdx.x * 64; n0 = blockIdx.y * 64;
    } else {
        int lin = blockIdx.x * 8 + blockIdx.y;
        if (lin >= 256) return;                 // value GEMM needs 256 tiles
        A = Wv; Bm = Z; C = vtb;
        m0 = (lin >> 6) * 64; n0 = (lin & 63) * 64;
    }
    const int tid  = threadIdx.x;
    const int wave = tid >> 6;
    const int lane = tid & 63;
    const int quad = lane >> 4;
    const int l15  = lane & 15;

    f32x4 acc[4];
    #pragma unroll
    for (int n = 0; n < 4; ++n) { acc[n][0]=0.f; acc[n][1]=0.f; acc[n][2]=0.f; acc[n][3]=0.f; }

    float4 ra[8], rb[8];
    #pragma unroll
    for (int it = 0; it < 8; ++it) {            // prefetch kc=0
        int f = it*1024 + tid*4, row = f >> 7, col = f & 127;
        ra[it] = *(const float4*)(A  + (size_t)(m0+row)*DDIM + col);
        rb[it] = *(const float4*)(Bm + (size_t)(n0+row)*DDIM + col);
    }

    for (int kc = 0; kc < DDIM; kc += 128) {
        __syncthreads();                        // LDS free (prev MFMA done)
        #pragma unroll
        for (int it = 0; it < 8; ++it) {
            int f = it*1024 + tid*4;
            bf16x4 a4; a4[0]=f2bf(ra[it].x); a4[1]=f2bf(ra[it].y); a4[2]=f2bf(ra[it].z); a4[3]=f2bf(ra[it].w);
            *(bf16x4*)(sA + f) = a4;
            bf16x4 b4; b4[0]=f2bf(rb[it].x); b4[1]=f2bf(rb[it].y); b4[2]=f2bf(rb[it].z); b4[3]=f2bf(rb[it].w);
            *(bf16x4*)(sB + f) = b4;
        }
        __syncthreads();                        // staged visible
        if (kc + 128 < DDIM) {                  // prefetch kc+1 (in flight under MFMA)
            #pragma unroll
            for (int it = 0; it < 8; ++it) {
                int f = it*1024 + tid*4, row = f >> 7, col = f & 127;
                ra[it] = *(const float4*)(A  + (size_t)(m0+row)*DDIM + kc + 128 + col);
                rb[it] = *(const float4*)(Bm + (size_t)(n0+row)*DDIM + kc + 128 + col);
            }
        }
        #pragma unroll
        for (int t = 0; t < 4; ++t) {
            bf16x8 af = *(const bf16x8*)(sA + (wave*16 + l15)*128 + t*32 + quad*8);
            #pragma unroll
            for (int n = 0; n < 4; ++n) {
                bf16x8 bfr = *(const bf16x8*)(sB + (n*16 + l15)*128 + t*32 + quad*8);
                acc[n] = __builtin_amdgcn_mfma_f32_16x16x32_bf16(af, bfr, acc[n], 0, 0, 0);
            }
        }
    }
    // packed epilogue
    #pragma unroll
    for (int n = 0; n < 4; ++n)
        #pragma unroll
        for (int r = 0; r < 4; ++r) {
            int m  = m0 + wave*16 + quad*4 + r;
            int nn = n0 + n*16 + l15;
            unsigned short v = (unsigned short)f2bf(acc[n][r]);
            size_t off;
            if (kpath) {        // s=m (key row), d=nn
                int J = m >> 6, kh = (m >> 5) & 1, ls = m & 31;
                int c = nn >> 7, tp = (nn >> 4) & 7, hd = (nn >> 3) & 1, d7 = nn & 7;
                off = (size_t)(((J*4 + c)*8 + tp)*2 + kh)*512 + (hd*32 + ls)*8 + d7;
            } else {            // dv=m, key=nn
                int J = nn >> 6, g = (nn >> 4) & 3, hk = (nn >> 3) & 1, k7 = nn & 7;
                int wv = m >> 7, n2 = (m >> 5) & 3, lv = m & 31;
                off = (size_t)((J*8 + wv*4 + n2)*4 + g)*512 + (hk*32 + lv)*8 + k7;
            }
            C[off] = v;
        }
}

// ---------------------------------------------------------------------------
// Fused attention, R10: J-PIPELINED (T15). R9 diagnosis: dependency-chain-
// bound — QK(j) -> softmax(j) -> PV(j) serial per wave, matrix pipe idle 75%.
// Fix: QK(j+1) is independent of softmax(j)/PV(j); interleave:
//   A: tmax(j) store        | B: QK(j+1) ph0-3   (fills BAR1 wait)
//   BAR1                    | C: exp2/pf(j) build+store
//   D1: QK(j+1) ph4-5       | BAR2
//   E: l/m update, rescale  | F: PV(j)
//   D2: QK(j+1) ph6-7 + V(j+2... V(j+1)) load AFTER F (V single-buffered)
// s double-buffered via j-unroll-by-2 (static reg names, rule #20); V single
// bank (reloaded at D2, after F consumed it) saves 64 arch VGPRs.
// All exchange windows cross exactly one barrier (verified per slot).
// Everything else identical to R9: 64 Q-rows/wave, packed coalesced K/V to
// regs, Q in LDS, T13 defer-max log2 softmax, XCD-split swizzle.
// grid = 512 (2 blocks/CU), block = 128 (one wk pair), launch_bounds(128,1).
// ---------------------------------------------------------------------------
__global__ __launch_bounds__(128, 1) void attn_fused(
    const float* __restrict__ X,            // [16384][512] fp32
    const unsigned short* __restrict__ Kb,  // key bf16, PACKED (4 MB)
    const unsigned short* __restrict__ Vt,  // V^T bf16, PACKED (2 MB)
    float* __restrict__ Opart,              // [NS][16384][256]
    float* __restrict__ Mpart,              // [NS][16384] (log2 domain)
    float* __restrict__ Lpart)              // [NS][16384]
{
    // 0     : sQ 64KB [rg=2][t2=32][lane]x16B
    // 65536 : sPex 8KB [g2*4 + wk*2 + ks][lane]x16B P A-frags
    // 73728 : sSt 1KB [(wk*2+g2)*2 + slot][32] floats
    __shared__ __align__(16) char smem[74752];
    char* sQ   = smem;
    char* sPex = smem + 65536;
    float* sSt = (float*)(smem + 73728);

    const int tid  = threadIdx.x;
    const int wk   = tid >> 6;      // 0..1: key-half for QK / dv-half for PV
    const int lane = tid & 63;
    const int l31  = lane & 31;
    const int hi   = lane >> 5;

    // XCD-split swizzle: bid&7 = XCD; XCD 0-3 -> split 0, 4-7 -> split 1.
    const int bid   = blockIdx.x;          // 0..511
    const int xcd   = bid & 7;
    const int slot  = bid >> 3;            // 0..63
    const int split = xcd >> 2;
    const int q0    = ((xcd & 3)*64 + slot) * 64;   // 64 rows/block
    // 1/sqrt(512) * log2(e): softmax runs in log2 domain (exp2)
    const float scale = 0.04419417382415922f * 1.4426950408889634f;

    // ---- prologue: wave wk stages row-group rg=wk's 32 Q frag-tiles ----
    {
        const float* xrow = X + (size_t)(q0 + wk*32 + l31)*DDIM + hi*8;
        char* qst = sQ + wk*32768;
        #pragma unroll
        for (int t2 = 0; t2 < 32; ++t2) {
            float4 a = *(const float4*)(xrow + t2*16);
            float4 b = *(const float4*)(xrow + t2*16 + 4);
            bf16x8 q;
            q[0]=f2bf(a.x*scale); q[1]=f2bf(a.y*scale); q[2]=f2bf(a.z*scale); q[3]=f2bf(a.w*scale);
            q[4]=f2bf(b.x*scale); q[5]=f2bf(b.y*scale); q[6]=f2bf(b.z*scale); q[7]=f2bf(b.w*scale);
            *(bf16x8*)(qst + t2*1024 + lane*16) = q;
        }
    }

    // O acc: [q32][n] D[row=q][col=dv], dv-half = wk*128 + n*32 + l31 (AGPR).
    f32x16 o[2][4];
    #pragma unroll
    for (int g2 = 0; g2 < 2; ++g2)
        #pragma unroll
        for (int n = 0; n < 4; ++n)
            #pragma unroll
            for (int r = 0; r < 16; ++r) o[g2][n][r] = 0.f;
    float m_r[2] = {-1e30f, -1e30f};
    float l_r[2] = {0.f, 0.f};

    // packed base pointers (this wave's key-half / dv-half, lane folded in)
    const int Jg0 = split * NJ;
    const char* kp = (const char*)Kb + (size_t)Jg0*65536 + wk*1024 + lane*16;
    const char* vp = (const char*)Vt + (size_t)Jg0*32768 + wk*16384 + lane*16;
    #define KOFF(h_, t_) ((size_t)((h_)>>1)*16384 + (size_t)((((h_)&1)*4 + (t_))*2)*1024)

    bf16x8 kf[3][4];                    // global half-chunk ring (48 VGPR)
    bf16x8 vf[4][4];                    // single V bank (64 VGPR)
    f32x16 sA_[2], sB_[2];              // s double buffer

    BAR_LGKM();                         // Q visible to the pair

    #define LD_KF(buf_, h_)                                                   \
        do { _Pragma("unroll")                                                \
             for (int t_ = 0; t_ < 4; ++t_)                                   \
                 kf[buf_][t_] = *(const bf16x8*)(kp + KOFF(h_, t_));          \
        } while (0)

    // load V windows half_ (0: g=0,1; 1: g=2,3) for tile at vp + voff_
    #define LD_V(half_, voff_)                                                \
        do { _Pragma("unroll")                                                \
             for (int gg_ = 0; gg_ < 2; ++gg_)                                \
                 _Pragma("unroll")                                            \
                 for (int n_ = 0; n_ < 4; ++n_)                               \
                     vf[(half_)*2 + gg_][n_] = *(const bf16x8*)(vp + (voff_)  \
                         + n_*4096 + ((half_)*2 + gg_)*1024);                 \
        } while (0)

    const char* qb = sQ + lane*16;

    // one QK phase: 8 MFMAs (2 row-groups) consuming kf[buf_], Q k-step h_
    #define QK_PH(SN_, buf_, h_)                                              \
        do {                                                                  \
            __builtin_amdgcn_s_setprio(1);                                    \
            _Pragma("unroll")                                                 \
            for (int t_ = 0; t_ < 4; ++t_) {                                  \
                bf16x8 q0_ = *(const bf16x8*)(qb + ((h_)*4 + t_)*1024);       \
                bf16x8 q1_ = *(const bf16x8*)(qb + 32768 + ((h_)*4 + t_)*1024);\
                SN_[0] = __builtin_amdgcn_mfma_f32_32x32x16_bf16(             \
                            kf[buf_][t_], q0_, SN_[0], 0, 0, 0);              \
                SN_[1] = __builtin_amdgcn_mfma_f32_32x32x16_bf16(             \
                            kf[buf_][t_], q1_, SN_[1], 0, 0, 0);              \
            }                                                                 \
            __builtin_amdgcn_s_setprio(0);                                    \
        } while (0)

    // ---- prologue: QK(0) -> sA_, V(0) -> vf; then kf ready for QK(1) ----
    LD_KF(0, 0); LD_KF(1, 1);
    #pragma unroll
    for (int g2 = 0; g2 < 2; ++g2)
        #pragma unroll
        for (int r = 0; r < 16; ++r) sA_[g2][r] = 0.f;
    LD_KF(2, 2); QK_PH(sA_, 0, 0);
    LD_KF(0, 3); QK_PH(sA_, 1, 1);
    LD_KF(1, 4); QK_PH(sA_, 2, 2);
    LD_KF(2, 5); QK_PH(sA_, 0, 3);
    LD_KF(0, 6); QK_PH(sA_, 1, 4);
    LD_KF(1, 7); QK_PH(sA_, 2, 5);
    LD_V(0, 0);  QK_PH(sA_, 0, 6);
    LD_V(1, 0);  QK_PH(sA_, 1, 7);
    kp += 65536;
    LD_KF(0, 0); LD_KF(1, 1);           // (1,0),(1,1) for ITER(0)'s B

    // ---------------- pipelined iteration ----------------
    #define ITER(jv, SC, SN)                                                  \
    {                                                                         \
        const bool hasN = (jv) + 1 < NJ;                                      \
        /* A: per-rg tile max of SC, store slot0 */                           \
        float tmx[2];                                                         \
        _Pragma("unroll")                                                     \
        for (int g2 = 0; g2 < 2; ++g2) {                                      \
            float v = fmaxf(fmaxf(fmaxf(SC[g2][0],SC[g2][1]),fmaxf(SC[g2][2],SC[g2][3])), \
                            fmaxf(fmaxf(SC[g2][4],SC[g2][5]),fmaxf(SC[g2][6],SC[g2][7]))); \
            v = fmaxf(v, fmaxf(fmaxf(fmaxf(SC[g2][8],SC[g2][9]),fmaxf(SC[g2][10],SC[g2][11])), \
                               fmaxf(fmaxf(SC[g2][12],SC[g2][13]),fmaxf(SC[g2][14],SC[g2][15])))); \
            v = fmaxf(v, __shfl_xor(v, 32));                                  \
            tmx[g2] = v;                                                      \
            if (lane < 32) sSt[((wk*2 + g2)*2 + 0)*32 + lane] = v;            \
        }                                                                     \
        /* B: QK(jv+1) phases 0-3 into SN (hides BAR1 wait) */                \
        if (hasN) {                                                           \
            _Pragma("unroll")                                                 \
            for (int g2 = 0; g2 < 2; ++g2)                                    \
                _Pragma("unroll")                                             \
                for (int r = 0; r < 16; ++r) SN[g2][r] = 0.f;                 \
            LD_KF(2, 2); QK_PH(SN, 0, 0);                                     \
            LD_KF(0, 3); QK_PH(SN, 1, 1);                                     \
            LD_KF(1, 4); QK_PH(SN, 2, 2);                                     \
            LD_KF(2, 5); QK_PH(SN, 0, 3);                                     \
        }                                                                     \
        BAR_LGKM();                                         /* exchange 1 */  \
        /* C: mn/upd/exp2/tsum + pf build + stores */                         \
        bool upd[2]; float mn[2], tsum[2], alpha[2];                          \
        bf16x8 pf[2][2];                                                      \
        _Pragma("unroll")                                                     \
        for (int g2 = 0; g2 < 2; ++g2) {                                      \
            float to = sSt[(((wk^1)*2 + g2)*2 + 0)*32 + l31];                 \
            float tj = fmaxf(tmx[g2], to);                                    \
            upd[g2] = tj > m_r[g2] + 8.0f;      /* T13 defer-max */           \
            mn[g2]  = upd[g2] ? tj : m_r[g2];                                 \
            alpha[g2] = upd[g2] ? exp2f(m_r[g2] - mn[g2]) : 1.0f;             \
            float ts = 0.f;                                                   \
            _Pragma("unroll")                                                 \
            for (int r = 0; r < 16; ++r) {                                    \
                float pv = exp2f(SC[g2][r] - mn[g2]); SC[g2][r] = pv; ts += pv; \
            }                                                                 \
            ts += __shfl_xor(ts, 32);                                         \
            tsum[g2] = ts;                                                    \
            if (lane < 32) sSt[((wk*2 + g2)*2 + 1)*32 + lane] = ts;           \
            _Pragma("unroll")                                                 \
            for (int ks = 0; ks < 2; ++ks) {                                  \
                int wA, wB, wC, wD;                                           \
                asm("v_cvt_pk_bf16_f32 %0, %1, %2" : "=v"(wA) : "v"(SC[g2][8*ks+0]), "v"(SC[g2][8*ks+1])); \
                asm("v_cvt_pk_bf16_f32 %0, %1, %2" : "=v"(wB) : "v"(SC[g2][8*ks+2]), "v"(SC[g2][8*ks+3])); \
                asm("v_cvt_pk_bf16_f32 %0, %1, %2" : "=v"(wC) : "v"(SC[g2][8*ks+4]), "v"(SC[g2][8*ks+5])); \
                asm("v_cvt_pk_bf16_f32 %0, %1, %2" : "=v"(wD) : "v"(SC[g2][8*ks+6]), "v"(SC[g2][8*ks+7])); \
                asm("v_permlane32_swap_b32 %0, %1" : "+v"(wA), "+v"(wC));     \
                asm("v_permlane32_swap_b32 %0, %1" : "+v"(wB), "+v"(wD));     \
                union { int w[4]; bf16x8 v; } u;                              \
                u.w[0] = wA; u.w[1] = wB; u.w[2] = wC; u.w[3] = wD;           \
                pf[g2][ks] = u.v;                                             \
                *(bf16x8*)(sPex + (g2*4 + wk*2 + ks)*1024 + lane*16) = u.v;   \
            }                                                                 \
        }                                                                     \
        /* D1: QK(jv+1) phases 4-5 (hides BAR2 wait) */                       \
        if (hasN) {                                                           \
            LD_KF(0, 6); QK_PH(SN, 1, 4);                                     \
            LD_KF(1, 7); QK_PH(SN, 2, 5);                                     \
        }                                                                     \
        BAR_LGKM();                                         /* exchange 2 */  \
        /* E: l/m update + O rescale (before PV accumulation) */              \
        _Pragma("unroll")                                                     \
        for (int g2 = 0; g2 < 2; ++g2) {                                      \
            float tso = sSt[(((wk^1)*2 + g2)*2 + 1)*32 + l31];                \
            l_r[g2] = l_r[g2]*alpha[g2] + (tsum[g2] + tso);                   \
            m_r[g2] = mn[g2];                                                 \
            if (__any(upd[g2])) {                                             \
                _Pragma("unroll")                                             \
                for (int r = 0; r < 16; ++r) {                                \
                    int row = (r&3) + 8*(r>>2) + 4*hi;                        \
                    float ar = __shfl(alpha[g2], row);                        \
                    _Pragma("unroll")                                         \
                    for (int n = 0; n < 4; ++n) o[g2][n][r] *= ar;            \
                }                                                             \
            }                                                                 \
        }                                                                     \
        /* F: PV(jv) with vf (V(jv)) + pf/sPex; partner pf safe after BAR2 */ \
        {                                                                     \
            const char* pb_ = sPex + lane*16;                                 \
            __builtin_amdgcn_s_setprio(1);                                    \
            _Pragma("unroll")                                                 \
            for (int g = 0; g < 4; ++g) {                                     \
                bf16x8 pa0 = ((g >> 1) == wk) ? pf[0][g & 1]                  \
                            : *(const bf16x8*)(pb_ + (0*4 + g)*1024);         \
                bf16x8 pa1 = ((g >> 1) == wk) ? pf[1][g & 1]                  \
                            : *(const bf16x8*)(pb_ + (1*4 + g)*1024);         \
                _Pragma("unroll")                                             \
                for (int n = 0; n < 4; ++n) {                                 \
                    o[0][n] = __builtin_amdgcn_mfma_f32_32x32x16_bf16(        \
                            pa0, vf[g][n], o[0][n], 0, 0, 0);                 \
                    o[1][n] = __builtin_amdgcn_mfma_f32_32x32x16_bf16(        \
                            pa1, vf[g][n], o[1][n], 0, 0, 0);                 \
                }                                                             \
            }                                                                 \
            __builtin_amdgcn_s_setprio(0);                                    \
        }                                                                     \
        /* D2: QK(jv+1) phases 6-7; V(jv+1) reload AFTER F freed vf */        \
        if (hasN) {                                                           \
            LD_V(0, 32768); QK_PH(SN, 0, 6);                                  \
            LD_V(1, 32768); QK_PH(SN, 1, 7);                                  \
            kp += 65536;                                                      \
            if ((jv) + 2 < NJ) { LD_KF(0, 0); LD_KF(1, 1); }                  \
        }                                                                     \
        vp += 32768;                                                          \
    }

    for (int j = 0; j < NJ; j += 2) {
        ITER(j,     sA_, sB_);
        ITER(j + 1, sB_, sA_);
    }
    #undef ITER
    #undef QK_PH
    #undef LD_V
    #undef LD_KF
    #undef KOFF

    // ---- epilogue: shared (m,l) across wk; disjoint dv halves -> no merge ----
    const size_t base = (size_t)split * NROWS;
    #pragma unroll
    for (int g2 = 0; g2 < 2; ++g2) {
        const int gr0 = q0 + g2*32;
        if (wk == 0 && lane < 32) {
            Mpart[base + gr0 + lane] = m_r[g2];     // log2 domain
            Lpart[base + gr0 + lane] = l_r[g2];
        }
        #pragma unroll
        for (int r = 0; r < 16; ++r) {
            int row = (r&3) + 8*(r>>2) + 4*hi;
            float* orow = Opart + (base + gr0 + row) * (size_t)DVDIM + wk*128;
            #pragma unroll
            for (int n = 0; n < 4; ++n)
                orow[n*32 + l31] = o[g2][n][r];
        }
    }
}

// ---------------------------------------------------------------------------
// Combine NS split partials: out = sum_s(Os*ws) / sum_s(ls*ws), ws=2^(ms-M)
// (Mpart is log2-domain). grid = NROWS/4, block = 256. Coalesced.
// ---------------------------------------------------------------------------
__global__ void combine_splits(
    const float* __restrict__ Opart, const float* __restrict__ Mpart,
    const float* __restrict__ Lpart, float* __restrict__ out)
{
    const int row = blockIdx.x * 4 + (threadIdx.x >> 6);
    const int dv4 = (threadIdx.x & 63) * 4;
    float M = -1e30f;
    #pragma unroll
    for (int s = 0; s < NS; ++s) M = fmaxf(M, Mpart[(size_t)s*NROWS + row]);
    float denom = 0.f;
    float4 acc = make_float4(0.f, 0.f, 0.f, 0.f);
    #pragma unroll
    for (int s = 0; s < NS; ++s) {
        float w = exp2f(Mpart[(size_t)s*NROWS + row] - M);
        denom += Lpart[(size_t)s*NROWS + row] * w;
        float4 ov = *(const float4*)(Opart + ((size_t)s*NROWS + row)*DVDIM + dv4);
        acc.x += ov.x*w; acc.y += ov.y*w; acc.z += ov.z*w; acc.w += ov.w*w;
    }
    float inv = 1.0f / denom;
    *(float4*)(out + (size_t)row*DVDIM + dv4)
        = make_float4(acc.x*inv, acc.y*inv, acc.z*inv, acc.w*inv);
}

extern "C" void kernel_launch(void* const* d_in, const int* in_sizes, int n_in,
                              void* d_out, int out_size, void* d_ws, size_t ws_size,
                              hipStream_t stream) {
    const float* X  = (const float*)d_in[0];   // [8,2048,512]
    const float* Y  = (const float*)d_in[1];   // [4096,512]
    const float* Z  = (const float*)d_in[2];   // [4096,512]
    const float* Wk = (const float*)d_in[3];   // [512,512]
    const float* Wv = (const float*)d_in[4];   // [256,512]
    float* out = (float*)d_out;

    // workspace layout (~38.3 MB)
    char* ws = (char*)d_ws;
    unsigned short* keyb = (unsigned short*)ws;                    // 4 MB, PACKED
    unsigned short* vtb  = (unsigned short*)(ws + (4u<<20));       // 2 MB, PACKED
    float* Opart = (float*)(ws + (6u<<20));                        // NS x 16 MB
    float* Mpart = (float*)(ws + (6u<<20) + (size_t)NS*NROWS*DVDIM*4);
    float* Lpart = Mpart + (size_t)NS*NROWS;

    // both projections, one launch (epilogues emit packed layouts)
    proj_gemms<<<dim3(64, 8, 2), dim3(256), 0, stream>>>(Y, Z, Wk, Wv, keyb, vtb);
    // fused attention: 512 blocks (2/CU), j-pipelined, packed K/V to regs
    attn_fused<<<dim3(512), dim3(128), 0, stream>>>(
        X, keyb, vtb, Opart, Mpart, Lpart);
    // merge splits
    combine_splits<<<dim3(NROWS/4), dim3(256), 0, stream>>>(Opart, Mpart, Lpart, out);
}